// Round 7
// baseline (263.436 us; speedup 1.0000x reference)
//
#include <hip/hip_runtime.h>

#define BATCH 4
#define CIN   1024
#define CI    256
#define CO    1024
#define NSP   4096

typedef __attribute__((ext_vector_type(8))) short bf16x8;
typedef __attribute__((ext_vector_type(4))) float f32x4;
typedef __attribute__((ext_vector_type(2))) unsigned uint2v;

struct __align__(8) us4 { unsigned short x, y, z, w; };

#define DEVI __device__ __forceinline__

DEVI unsigned short f2bf(float f) {
  union { float f; unsigned u; } un; un.f = f;
  unsigned u = un.u;
  u += 0x7FFFu + ((u >> 16) & 1u);   // RNE
  return (unsigned short)(u >> 16);
}

// pack two f32 -> two bf16 (RNE), single instruction; lo -> bits[15:0]
DEVI unsigned cvtpk(float lo, float hi) {
  unsigned r;
  asm("v_cvt_pk_bf16_f32 %0, %1, %2" : "=v"(r) : "v"(lo), "v"(hi));
  return r;
}

DEVI void gl2lds16(const void* g, void* l) {
  __builtin_amdgcn_global_load_lds(
      (const __attribute__((address_space(1))) void*)g,
      (__attribute__((address_space(3))) void*)l, 16, 0, 0);
}

DEVI f32x4 mfma16(bf16x8 a, bf16x8 b, f32x4 c) {
  return __builtin_amdgcn_mfma_f32_16x16x32_bf16(a, b, c, 0, 0, 0);
}

// ----------------------------------------- x transpose -> bf16, + prep fused
// blocks [0,2048): weight/bn prep.  blocks [2048,6144): x transpose.
__global__ __launch_bounds__(256) void k_xpose_prep(
    const float* __restrict__ x, unsigned short* __restrict__ xT,
    const float* __restrict__ w_key, const float* __restrict__ w_val,
    const float* __restrict__ w_out,
    const float* __restrict__ gamma, const float* __restrict__ beta,
    const float* __restrict__ mean,  const float* __restrict__ var,
    const float* __restrict__ b_key,
    unsigned short* __restrict__ wkv, unsigned short* __restrict__ wob,
    float* __restrict__ sq, float* __restrict__ bq)
{
  int bid = blockIdx.x;
  if (bid < 2048) {                              // ---- prep half
    int idx = bid * 256 + threadIdx.x;           // 0 .. 524287
    float wv = (idx < 262144) ? w_key[idx] : w_val[idx - 262144];
    wkv[idx] = f2bf(wv);
    if (idx < 262144) wob[idx] = f2bf(w_out[idx]);
    if (idx < 256) {
      float inv = gamma[idx] * rsqrtf(var[idx] + 1e-5f);
      sq[idx] = 0.25f * inv;                     // sqrt(1/16) folded into qk
      bq[idx] = 0.25f * (beta[idx] + (b_key[idx] - mean[idx]) * inv);
    }
    return;
  }
  // ---- transpose half
  __shared__ unsigned short tile[64][66];        // stride 66: u32-aligned rows
  int id2 = bid - 2048;
  int b = id2 >> 10, k0 = ((id2 >> 6) & 15) * 64, n0 = (id2 & 63) * 64;
  int tid = threadIdx.x;
  int rr = tid >> 4, cc = tid & 15;
  const float* xb = x + ((size_t)b * CIN + k0) * NSP + n0;
#pragma unroll
  for (int p = 0; p < 4; ++p) {
    int row = p * 16 + rr;
    float4 v = *(const float4*)(xb + (size_t)row * NSP + cc * 4);
    *(unsigned*)&tile[row][cc * 4 + 0] = cvtpk(v.x, v.y);
    *(unsigned*)&tile[row][cc * 4 + 2] = cvtpk(v.z, v.w);
  }
  __syncthreads();
  unsigned short* xtb = xT + ((size_t)b * NSP + n0) * CIN + k0;
#pragma unroll
  for (int p = 0; p < 4; ++p) {
    int n = p * 16 + rr;
    int kq = cc * 4;
    us4 pk;
    pk.x = tile[kq + 0][n]; pk.y = tile[kq + 1][n];
    pk.z = tile[kq + 2][n]; pk.w = tile[kq + 3][n];
    *(us4*)(xtb + (size_t)n * CIN + kq) = pk;
  }
}

// ------------------------------------------------- qk/value conv (fused)
// R11: 8-wave 256x128 NT tile, 512 threads, grid 256 = 1 block/CU.
// Block-level split: bid<128 -> qk (A = wkv rows 0..255 = all qk channels,
// B = 128-n xT panel, D[c][n]); bid>=128 -> value (A = 256-n xT panel,
// B = wkv value-channel half, D[n][c] -> packed 8B vv writes).
// Per wave 64x64 (acc[4][4]); MFMA:ds_read = 2:1; dbuf, one barrier/K-step.
__global__ __launch_bounds__(512, 2) void k_convqkv(
    const unsigned short* __restrict__ wkv,   // [512][1024]
    const unsigned short* __restrict__ xT,    // [B][4096][1024]
    const float* __restrict__ sq, const float* __restrict__ bq,
    const float* __restrict__ bval,
    unsigned short* __restrict__ qkT,         // [B][4096][256]
    unsigned short* __restrict__ vv)          // [B][256][4096]
{
  __shared__ __align__(16) unsigned short ldsA[2 * 256 * 64];  // 64 KB
  __shared__ __align__(16) unsigned short ldsB[2 * 128 * 64];  // 32 KB

  int bid = blockIdx.x;                      // 0..255
  int tid = threadIdx.x;
  const int lane = tid & 63, wave = tid >> 6;          // wave 0..7
  const int q = lane >> 4, ln = lane & 15;
  const int wm = wave & 3, wn = wave >> 2;             // 4 m-quarters x 2 n-halves

  bool qk = (bid < 128);
  const unsigned short *Ab, *Bb;
  int b, n0, ch = 0;
  if (qk) {
    n0 = (bid & 31) * 128; b = bid >> 5;
    Ab = wkv;                                          // 256 qk channel rows
    Bb = xT + ((size_t)b * NSP + n0) * CIN;            // 128 n rows
  } else {
    int id2 = bid - 128;
    n0 = (id2 & 15) * 256; ch = ((id2 >> 4) & 1) * 128; b = id2 >> 5;
    Ab = xT + ((size_t)b * NSP + n0) * CIN;            // 256 n rows
    Bb = wkv + (size_t)(256 + ch) * CIN;               // 128 value-channel rows
  }

  int aoff[4][2], boff[4][2];
#pragma unroll
  for (int f = 0; f < 4; ++f) {
    int ra = wm * 64 + f * 16 + ln;
    aoff[f][0] = (ra * 8 + ((q)     ^ (ra & 7))) * 8;
    aoff[f][1] = (ra * 8 + ((q + 4) ^ (ra & 7))) * 8;
    int rb = wn * 64 + f * 16 + ln;
    boff[f][0] = (rb * 8 + ((q)     ^ (rb & 7))) * 8;
    boff[f][1] = (rb * 8 + ((q + 4) ^ (rb & 7))) * 8;
  }
  int sgA[4], sgB[2];
#pragma unroll
  for (int i = 0; i < 4; ++i) {
    int s = i * 512 + tid;
    int row = s >> 3;
    int c8 = (s & 7) ^ (row & 7);
    sgA[i] = row * CIN + c8 * 8;
  }
#pragma unroll
  for (int i = 0; i < 2; ++i) {
    int s = i * 512 + tid;
    int row = s >> 3;
    int c8 = (s & 7) ^ (row & 7);
    sgB[i] = row * CIN + c8 * 8;
  }

  // prologue: stage k0=0 into buffer 0
#pragma unroll
  for (int i = 0; i < 4; ++i)
    gl2lds16(Ab + sgA[i], ldsA + (i * 512 + wave * 64) * 8);
#pragma unroll
  for (int i = 0; i < 2; ++i)
    gl2lds16(Bb + sgB[i], ldsB + (i * 512 + wave * 64) * 8);
  __syncthreads();

  f32x4 z = {0.f, 0.f, 0.f, 0.f};
  f32x4 acc[4][4];
#pragma unroll
  for (int i = 0; i < 4; ++i)
#pragma unroll
    for (int j = 0; j < 4; ++j) acc[i][j] = z;

  for (int k0 = 0; k0 < CIN; k0 += 64) {
    const int cur = (k0 >> 6) & 1;
    const unsigned short* A = ldsA + cur * (256 * 64);
    const unsigned short* B = ldsB + cur * (128 * 64);
    if (k0 + 64 < CIN) {
      unsigned short* An = ldsA + (cur ^ 1) * (256 * 64);
      unsigned short* Bn = ldsB + (cur ^ 1) * (128 * 64);
#pragma unroll
      for (int i = 0; i < 4; ++i)
        gl2lds16(Ab + sgA[i] + k0 + 64, An + (i * 512 + wave * 64) * 8);
#pragma unroll
      for (int i = 0; i < 2; ++i)
        gl2lds16(Bb + sgB[i] + k0 + 64, Bn + (i * 512 + wave * 64) * 8);
    }
    __builtin_amdgcn_s_setprio(1);
#pragma unroll
    for (int kk = 0; kk < 2; ++kk) {
      bf16x8 af[4], bfr[4];
#pragma unroll
      for (int f = 0; f < 4; ++f) af[f]  = *(const bf16x8*)(A + aoff[f][kk]);
#pragma unroll
      for (int f = 0; f < 4; ++f) bfr[f] = *(const bf16x8*)(B + boff[f][kk]);
#pragma unroll
      for (int mf = 0; mf < 4; ++mf)
#pragma unroll
        for (int nf = 0; nf < 4; ++nf)
          acc[mf][nf] = mfma16(af[mf], bfr[nf], acc[mf][nf]);
    }
    __builtin_amdgcn_s_setprio(0);
    __syncthreads();
  }

  if (qk) {
    // D rows = qk channels, cols = spatial n
#pragma unroll
    for (int mf = 0; mf < 4; ++mf) {
      int cb = wm * 64 + mf * 16 + q * 4;
      float s0_ = sq[cb + 0], s1_ = sq[cb + 1], s2_ = sq[cb + 2], s3_ = sq[cb + 3];
      float b0_ = bq[cb + 0], b1_ = bq[cb + 1], b2_ = bq[cb + 2], b3_ = bq[cb + 3];
#pragma unroll
      for (int nf = 0; nf < 4; ++nf) {
        int n = n0 + wn * 64 + nf * 16 + ln;
        uint2v pk2;
        pk2.x = cvtpk(acc[mf][nf][0] * s0_ + b0_, acc[mf][nf][1] * s1_ + b1_);
        pk2.y = cvtpk(acc[mf][nf][2] * s2_ + b2_, acc[mf][nf][3] * s3_ + b3_);
        *(uint2v*)(qkT + ((size_t)b * NSP + n) * CI + cb) = pk2;
      }
    }
  } else {
    // D rows = spatial n, cols = value channels
#pragma unroll
    for (int nf = 0; nf < 4; ++nf) {
      int c = ch + wn * 64 + nf * 16 + ln;
      float bv = bval[c];
      unsigned short* vr = vv + ((size_t)b * CI + c) * NSP + n0 + wm * 64 + q * 4;
#pragma unroll
      for (int mf = 0; mf < 4; ++mf) {
        uint2v wv2;
        wv2.x = cvtpk(acc[mf][nf][0] + bv, acc[mf][nf][1] + bv);
        wv2.y = cvtpk(acc[mf][nf][2] + bv, acc[mf][nf][3] + bv);
        *(uint2v*)(vr + mf * 16) = wv2;
      }
    }
  }
}

// ------------------------------------------------- fused attention, partial
// unchanged (no-max softmax, dbuf K/V, packed bf16 partials)
__global__ __launch_bounds__(256, 2) void k_attn_part(
    const unsigned short* __restrict__ qkT,   // [B][4096][256]
    const unsigned short* __restrict__ vv,    // [B][256][4096]
    unsigned* __restrict__ Opart,             // [512][64 rowpair][256] u32
    float* __restrict__ Lpart)                // [512][128]
{
  __shared__ __align__(16) unsigned short Kt[2][32 * 256]; // [32 j][32 cc] swz
  __shared__ __align__(16) unsigned short Vt[2][256 * 32]; // [256 c][4 cc] swz
  __shared__ __align__(16) unsigned short Pl[4 * 32 * 40]; // per-wave [32 m][40]

  int bid = blockIdx.x;                       // 512 blocks
  int slice = bid & 15, qt = bid >> 4;        // qt 0..31 (128 rows each)
  int b = slice >> 2, js = slice & 3;
  int n0 = qt * 128;
  int tid = threadIdx.x, lane = tid & 63, wave = tid >> 6;
  int q = lane >> 4, ln = lane & 15;
  const unsigned short* qkb = qkT + (size_t)b * NSP * CI;
  const unsigned short* vb  = vv  + (size_t)b * CI * NSP;

  bf16x8 Qf0[8], Qf1[8];
  {
    const unsigned short* qr0 = qkb + (size_t)(n0 + wave * 32 + ln) * CI + q * 8;
    const unsigned short* qr1 = qr0 + 16 * CI;
#pragma unroll
    for (int t = 0; t < 8; ++t) Qf0[t] = *(const bf16x8*)(qr0 + t * 32);
#pragma unroll
    for (int t = 0; t < 8; ++t) Qf1[t] = *(const bf16x8*)(qr1 + t * 32);
  }

  int kbA = (ln * 32 + ((q ^ (ln & 7)) & 7)) * 8;            // t even
  int kbB = (ln * 32 + (((4 + q) ^ (ln & 7)) & 7)) * 8;      // t odd
  int vbase = (ln * 4 + ((q ^ ((ln >> 1) & 3)) & 3)) * 8;

  unsigned short* Plw = Pl + wave * (32 * 40);
  int pw0 = ln * 40 + q * 4;
  int pw1 = ln * 40 + 16 + q * 4;
  int pw2 = (ln + 16) * 40 + q * 4;
  int pw3 = (ln + 16) * 40 + 16 + q * 4;
  int pr0 = ln * 40 + q * 8;
  int pr1 = (ln + 16) * 40 + q * 8;

  int gko[4], gvo[4];
#pragma unroll
  for (int i = 0; i < 4; ++i) {
    int s = i * 256 + tid;
    int j = s >> 5, f = s & 31;
    gko[i] = j * CI + ((f & 24) | ((f ^ j) & 7)) * 8;
    int c = s >> 2;
    gvo[i] = c * NSP + ((s ^ (c >> 1)) & 3) * 8;
  }

  f32x4 O0[16], O1[16];
  f32x4 z = {0.f, 0.f, 0.f, 0.f};
#pragma unroll
  for (int cf = 0; cf < 16; ++cf) { O0[cf] = z; O1[cf] = z; }
  float l0c = 0.f, l1c = 0.f;

  int jbase = js * 1024;

#pragma unroll
  for (int i = 0; i < 4; ++i)
    gl2lds16(qkb + (size_t)jbase * CI + gko[i], &Kt[0][(i * 256 + wave * 64) * 8]);
#pragma unroll
  for (int i = 0; i < 4; ++i)
    gl2lds16(vb + jbase + gvo[i], &Vt[0][(i * 256 + wave * 64) * 8]);
  __syncthreads();

  for (int it = 0; it < 32; ++it) {
    int cur = it & 1;

    if (it < 31) {
      int j1 = jbase + (it + 1) * 32;
#pragma unroll
      for (int i = 0; i < 4; ++i)
        gl2lds16(qkb + (size_t)j1 * CI + gko[i],
                 &Kt[cur ^ 1][(i * 256 + wave * 64) * 8]);
#pragma unroll
      for (int i = 0; i < 4; ++i)
        gl2lds16(vb + j1 + gvo[i],
                 &Vt[cur ^ 1][(i * 256 + wave * 64) * 8]);
    }

    const unsigned short* Kc = Kt[cur];
    const unsigned short* Vc = Vt[cur];

    f32x4 s0 = z, s1 = z, s2 = z, s3 = z;
    __builtin_amdgcn_s_setprio(1);
#pragma unroll
    for (int t = 0; t < 8; ++t) {
      int ko = ((t & 1) ? kbB : kbA) + (t >> 1) * 64;
      bf16x8 kf0 = *(const bf16x8*)(Kc + ko);
      bf16x8 kf1 = *(const bf16x8*)(Kc + ko + 4096);
      s0 = mfma16(kf0, Qf0[t], s0);
      s1 = mfma16(kf1, Qf0[t], s1);
      s2 = mfma16(kf0, Qf1[t], s2);
      s3 = mfma16(kf1, Qf1[t], s3);
    }
    __builtin_amdgcn_s_setprio(0);

    float p00 = __expf(s0[0]), p01 = __expf(s0[1]);
    float p02 = __expf(s0[2]), p03 = __expf(s0[3]);
    float p04 = __expf(s1[0]), p05 = __expf(s1[1]);
    float p06 = __expf(s1[2]), p07 = __expf(s1[3]);
    float p10 = __expf(s2[0]), p11 = __expf(s2[1]);
    float p12 = __expf(s2[2]), p13 = __expf(s2[3]);
    float p14 = __expf(s3[0]), p15 = __expf(s3[1]);
    float p16 = __expf(s3[2]), p17 = __expf(s3[3]);

    uint2v w;
    w.x = cvtpk(p00, p01); w.y = cvtpk(p02, p03);
    *(uint2v*)(Plw + pw0) = w;
    w.x = cvtpk(p04, p05); w.y = cvtpk(p06, p07);
    *(uint2v*)(Plw + pw1) = w;
    w.x = cvtpk(p10, p11); w.y = cvtpk(p12, p13);
    *(uint2v*)(Plw + pw2) = w;
    w.x = cvtpk(p14, p15); w.y = cvtpk(p16, p17);
    *(uint2v*)(Plw + pw3) = w;

    l0c += ((p00 + p01) + (p02 + p03)) + ((p04 + p05) + (p06 + p07));
    l1c += ((p10 + p11) + (p12 + p13)) + ((p14 + p15) + (p16 + p17));

    bf16x8 pf0 = *(const bf16x8*)(Plw + pr0);
    bf16x8 pf1 = *(const bf16x8*)(Plw + pr1);
    __builtin_amdgcn_s_setprio(1);
#pragma unroll
    for (int cf = 0; cf < 16; ++cf) {
      bf16x8 vf = *(const bf16x8*)(Vc + vbase + cf * 512);
      O0[cf] = mfma16(pf0, vf, O0[cf]);
      O1[cf] = mfma16(pf1, vf, O1[cf]);
    }
    __builtin_amdgcn_s_setprio(0);

    __syncthreads();
  }

  l0c += __shfl_xor(l0c, 16); l0c += __shfl_xor(l0c, 32);
  l1c += __shfl_xor(l1c, 16); l1c += __shfl_xor(l1c, 32);

  unsigned* Ob = Opart + (size_t)bid * (64 * 256);
  if (lane < 16) {
    Lpart[bid * 128 + wave * 32 + lane] = l0c;
    Lpart[bid * 128 + wave * 32 + 16 + lane] = l1c;
  }
#pragma unroll
  for (int r = 0; r < 4; ++r) {
    int rp = wave * 16 + q * 4 + r;
#pragma unroll
    for (int cf = 0; cf < 16; ++cf)
      Ob[rp * 256 + cf * 16 + ln] = cvtpk(O0[cf][r], O1[cf][r]);
  }
}

// ------------------------------------------------- split-k softmax merge
__global__ __launch_bounds__(256) void k_merge(
    const unsigned* __restrict__ Opart,       // [512][64][256] u32
    const float* __restrict__ Lpart,          // [512][128]
    unsigned short* __restrict__ ctx)         // [B][4096][256]
{
  __shared__ float Winv[64];
  int mb = blockIdx.x;                        // 256: one per (b, 64-row group)
  int b = mb >> 6, qg = mb & 63;
  int qt = qg >> 1, half = qg & 1;
  int tid = threadIdx.x;
  int pb0 = qt * 16 + b * 4;

  if (tid < 64) {
    int row = half * 64 + tid;
    float L = Lpart[(pb0 + 0) * 128 + row]
            + Lpart[(pb0 + 1) * 128 + row]
            + Lpart[(pb0 + 2) * 128 + row]
            + Lpart[(pb0 + 3) * 128 + row];
    Winv[tid] = 1.0f / L;
  }
  __syncthreads();

  const unsigned* P0 = Opart + ((size_t)(pb0 + 0) * 64 + half * 32) * 256;
  const unsigned* P1 = Opart + ((size_t)(pb0 + 1) * 64 + half * 32) * 256;
  const unsigned* P2 = Opart + ((size_t)(pb0 + 2) * 64 + half * 32) * 256;
  const unsigned* P3 = Opart + ((size_t)(pb0 + 3) * 64 + half * 32) * 256;
  unsigned short* cb = ctx + ((size_t)b * NSP + qg * 64) * CI;
#pragma unroll 4
  for (int rp = 0; rp < 32; ++rp) {
    unsigned u0 = P0[rp * 256 + tid], u1 = P1[rp * 256 + tid];
    unsigned u2 = P2[rp * 256 + tid], u3 = P3[rp * 256 + tid];
    float lo = __uint_as_float(u0 << 16) + __uint_as_float(u1 << 16)
             + __uint_as_float(u2 << 16) + __uint_as_float(u3 << 16);
    float hi = __uint_as_float(u0 & 0xFFFF0000u) + __uint_as_float(u1 & 0xFFFF0000u)
             + __uint_as_float(u2 & 0xFFFF0000u) + __uint_as_float(u3 & 0xFFFF0000u);
    int ra = (rp & 15) + ((rp >> 4) << 5);
    int rb = ra + 16;
    cb[(size_t)ra * CI + tid] = f2bf(lo * Winv[ra]);
    cb[(size_t)rb * CI + tid] = f2bf(hi * Winv[rb]);
  }
}

// ------------------------------------------------------ output conv
// R11: 8-wave 256x256 tile, 512 threads, grid 256 = 1 block/CU, dbuf
// (128 KB LDS). Per wave 128x64 (acc[8][4]); K=256 in 4 dbuf'd steps.
__global__ __launch_bounds__(512, 2) void k_convout(
    const unsigned short* __restrict__ wo,    // [1024][256]
    const unsigned short* __restrict__ ctx,   // [B][4096][256]
    const float* __restrict__ bout,
    float* __restrict__ out)                  // [B][1024][4096]
{
  __shared__ __align__(16) unsigned short ldsA[2 * 256 * 64];  // 64 KB
  __shared__ __align__(16) unsigned short ldsB[2 * 256 * 64];  // 64 KB
  int b = blockIdx.z, m0 = blockIdx.y * 256, n0 = blockIdx.x * 256;
  int tid = threadIdx.x;
  const int lane = tid & 63, wave = tid >> 6;          // 0..7
  const int q = lane >> 4, ln = lane & 15;
  const int wm = wave & 1, wn = wave >> 1;             // 2 m-halves x 4 n-quarters

  const unsigned short* Ab = wo + (size_t)m0 * CI;
  const unsigned short* Bb = ctx + ((size_t)b * NSP + n0) * CI;

  int aoff[8][2], boff[4][2];
#pragma unroll
  for (int f = 0; f < 8; ++f) {
    int ra = wm * 128 + f * 16 + ln;
    aoff[f][0] = (ra * 8 + ((q)     ^ (ra & 7))) * 8;
    aoff[f][1] = (ra * 8 + ((q + 4) ^ (ra & 7))) * 8;
  }
#pragma unroll
  for (int f = 0; f < 4; ++f) {
    int rb = wn * 64 + f * 16 + ln;
    boff[f][0] = (rb * 8 + ((q)     ^ (rb & 7))) * 8;
    boff[f][1] = (rb * 8 + ((q + 4) ^ (rb & 7))) * 8;
  }
  int sg[4];
#pragma unroll
  for (int i = 0; i < 4; ++i) {
    int s = i * 512 + tid;
    int row = s >> 3;
    int c8 = (s & 7) ^ (row & 7);
    sg[i] = row * CI + c8 * 8;
  }

  // prologue: stage k0=0 into buffer 0
#pragma unroll
  for (int i = 0; i < 4; ++i) {
    gl2lds16(Ab + sg[i], ldsA + (i * 512 + wave * 64) * 8);
    gl2lds16(Bb + sg[i], ldsB + (i * 512 + wave * 64) * 8);
  }
  __syncthreads();

  f32x4 z = {0.f, 0.f, 0.f, 0.f};
  f32x4 acc[8][4];
#pragma unroll
  for (int i = 0; i < 8; ++i)
#pragma unroll
    for (int j = 0; j < 4; ++j) acc[i][j] = z;

  for (int k0 = 0; k0 < CI; k0 += 64) {
    const int cur = (k0 >> 6) & 1;
    const unsigned short* A = ldsA + cur * (256 * 64);
    const unsigned short* B = ldsB + cur * (256 * 64);
    if (k0 + 64 < CI) {
      unsigned short* An = ldsA + (cur ^ 1) * (256 * 64);
      unsigned short* Bn = ldsB + (cur ^ 1) * (256 * 64);
#pragma unroll
      for (int i = 0; i < 4; ++i) {
        gl2lds16(Ab + sg[i] + k0 + 64, An + (i * 512 + wave * 64) * 8);
        gl2lds16(Bb + sg[i] + k0 + 64, Bn + (i * 512 + wave * 64) * 8);
      }
    }
    __builtin_amdgcn_s_setprio(1);
#pragma unroll
    for (int kk = 0; kk < 2; ++kk) {
      bf16x8 af[8], bfr[4];
#pragma unroll
      for (int f = 0; f < 8; ++f) af[f]  = *(const bf16x8*)(A + aoff[f][kk]);
#pragma unroll
      for (int f = 0; f < 4; ++f) bfr[f] = *(const bf16x8*)(B + boff[f][kk]);
#pragma unroll
      for (int mf = 0; mf < 8; ++mf)
#pragma unroll
        for (int nf = 0; nf < 4; ++nf)
          acc[mf][nf] = mfma16(af[mf], bfr[nf], acc[mf][nf]);
    }
    __builtin_amdgcn_s_setprio(0);
    __syncthreads();
  }

#pragma unroll
  for (int mf = 0; mf < 8; ++mf) {
    int cb = m0 + wm * 128 + mf * 16 + q * 4;
    float bo0 = bout[cb + 0], bo1 = bout[cb + 1], bo2 = bout[cb + 2], bo3 = bout[cb + 3];
#pragma unroll
    for (int nf = 0; nf < 4; ++nf) {
      int n = n0 + wn * 64 + nf * 16 + ln;
      float* p = out + ((size_t)b * CO + cb) * NSP + n;
      p[0 * (size_t)NSP] = acc[mf][nf][0] + bo0;
      p[1 * (size_t)NSP] = acc[mf][nf][1] + bo1;
      p[2 * (size_t)NSP] = acc[mf][nf][2] + bo2;
      p[3 * (size_t)NSP] = acc[mf][nf][3] + bo3;
    }
  }
}

// ---------------------------------------------------------------- launch
extern "C" void kernel_launch(void* const* d_in, const int* in_sizes, int n_in,
                              void* d_out, int out_size, void* d_ws, size_t ws_size,
                              hipStream_t stream) {
  const float* x     = (const float*)d_in[0];
  const float* w_key = (const float*)d_in[1];
  const float* b_key = (const float*)d_in[2];
  const float* gamma = (const float*)d_in[3];
  const float* beta  = (const float*)d_in[4];
  const float* mean  = (const float*)d_in[5];
  const float* var   = (const float*)d_in[6];
  const float* w_val = (const float*)d_in[7];
  const float* b_val = (const float*)d_in[8];
  const float* w_out = (const float*)d_in[9];
  const float* b_out = (const float*)d_in[10];
  float* out = (float*)d_out;

  char* ws = (char*)d_ws;
  unsigned short* xT  = (unsigned short*)(ws);               // 32 MiB
  unsigned short* wkv = (unsigned short*)(ws + 33554432);    // 1 MiB
  unsigned short* wob = (unsigned short*)(ws + 34603008);    // 512 KiB
  unsigned short* qkT = (unsigned short*)(ws + 35127296);    // 8 MiB
  unsigned short* vv  = (unsigned short*)(ws + 43515904);    // 8 MiB
  unsigned short* ctx = (unsigned short*)(ws + 51904512);    // 8 MiB
  float* sq = (float*)(ws + 60293120);                       // 1 KiB
  float* bq = (float*)(ws + 60294144);                       // 1 KiB
  unsigned* Opart = (unsigned*)(ws + 60295168);              // 32 MiB (packed)
  float* Lpart = (float*)(ws + 127404032);                   // 256 KiB

  k_xpose_prep<<<6144, 256, 0, stream>>>(x, xT, w_key, w_val, w_out, gamma,
                                         beta, mean, var, b_key, wkv, wob,
                                         sq, bq);
  k_convqkv<<<256, 512, 0, stream>>>(wkv, xT, sq, bq, b_val, qkT, vv);
  k_attn_part<<<512, 256, 0, stream>>>(qkT, vv, Opart, Lpart);
  k_merge<<<256, 256, 0, stream>>>(Opart, Lpart, ctx);
  k_convout<<<dim3(16, 4, 4), 512, 0, stream>>>(wob, ctx, b_out, out);
}

// Round 8
// 254.583 us; speedup vs baseline: 1.0348x; 1.0348x over previous
//
#include <hip/hip_runtime.h>

#define BATCH 4
#define CIN   1024
#define CI    256
#define CO    1024
#define NSP   4096

typedef __attribute__((ext_vector_type(8))) short bf16x8;
typedef __attribute__((ext_vector_type(4))) float f32x4;
typedef __attribute__((ext_vector_type(2))) unsigned uint2v;

struct __align__(8) us4 { unsigned short x, y, z, w; };

#define DEVI __device__ __forceinline__

DEVI unsigned short f2bf(float f) {
  union { float f; unsigned u; } un; un.f = f;
  unsigned u = un.u;
  u += 0x7FFFu + ((u >> 16) & 1u);   // RNE
  return (unsigned short)(u >> 16);
}

// pack two f32 -> two bf16 (RNE), single instruction; lo -> bits[15:0]
DEVI unsigned cvtpk(float lo, float hi) {
  unsigned r;
  asm("v_cvt_pk_bf16_f32 %0, %1, %2" : "=v"(r) : "v"(lo), "v"(hi));
  return r;
}

DEVI void gl2lds16(const void* g, void* l) {
  __builtin_amdgcn_global_load_lds(
      (const __attribute__((address_space(1))) void*)g,
      (__attribute__((address_space(3))) void*)l, 16, 0, 0);
}

DEVI f32x4 mfma16(bf16x8 a, bf16x8 b, f32x4 c) {
  return __builtin_amdgcn_mfma_f32_16x16x32_bf16(a, b, c, 0, 0, 0);
}

// ----------------------------------------- x transpose -> bf16, + prep fused
// blocks [0,2048): weight/bn prep.  blocks [2048,6144): x transpose.
__global__ __launch_bounds__(256) void k_xpose_prep(
    const float* __restrict__ x, unsigned short* __restrict__ xT,
    const float* __restrict__ w_key, const float* __restrict__ w_val,
    const float* __restrict__ w_out,
    const float* __restrict__ gamma, const float* __restrict__ beta,
    const float* __restrict__ mean,  const float* __restrict__ var,
    const float* __restrict__ b_key,
    unsigned short* __restrict__ wkv, unsigned short* __restrict__ wob,
    float* __restrict__ sq, float* __restrict__ bq)
{
  int bid = blockIdx.x;
  if (bid < 2048) {                              // ---- prep half
    int idx = bid * 256 + threadIdx.x;           // 0 .. 524287
    float wv = (idx < 262144) ? w_key[idx] : w_val[idx - 262144];
    wkv[idx] = f2bf(wv);
    if (idx < 262144) wob[idx] = f2bf(w_out[idx]);
    if (idx < 256) {
      float inv = gamma[idx] * rsqrtf(var[idx] + 1e-5f);
      sq[idx] = 0.25f * inv;                     // sqrt(1/16) folded into qk
      bq[idx] = 0.25f * (beta[idx] + (b_key[idx] - mean[idx]) * inv);
    }
    return;
  }
  // ---- transpose half
  __shared__ unsigned short tile[64][66];        // stride 66: u32-aligned rows
  int id2 = bid - 2048;
  int b = id2 >> 10, k0 = ((id2 >> 6) & 15) * 64, n0 = (id2 & 63) * 64;
  int tid = threadIdx.x;
  int rr = tid >> 4, cc = tid & 15;
  const float* xb = x + ((size_t)b * CIN + k0) * NSP + n0;
#pragma unroll
  for (int p = 0; p < 4; ++p) {
    int row = p * 16 + rr;
    float4 v = *(const float4*)(xb + (size_t)row * NSP + cc * 4);
    *(unsigned*)&tile[row][cc * 4 + 0] = cvtpk(v.x, v.y);
    *(unsigned*)&tile[row][cc * 4 + 2] = cvtpk(v.z, v.w);
  }
  __syncthreads();
  unsigned short* xtb = xT + ((size_t)b * NSP + n0) * CIN + k0;
#pragma unroll
  for (int p = 0; p < 4; ++p) {
    int n = p * 16 + rr;
    int kq = cc * 4;
    us4 pk;
    pk.x = tile[kq + 0][n]; pk.y = tile[kq + 1][n];
    pk.z = tile[kq + 2][n]; pk.w = tile[kq + 3][n];
    *(us4*)(xtb + (size_t)n * CIN + kq) = pk;
  }
}

// -------------------------------- 128x128 NT GEMM core, double-buffered
template<int KDIM>
DEVI void gemm_core_db(const unsigned short* __restrict__ Ab,
                       const unsigned short* __restrict__ Bb,
                       unsigned short* ldsA, unsigned short* ldsB, // [2][128*64]
                       f32x4 acc[4][4], int tid)
{
  const int lane = tid & 63, wave = tid >> 6;
  const int q = lane >> 4, ln = lane & 15;
  const int wm = wave & 1, wn = wave >> 1;

  int aoff[4][2], boff[4][2];
#pragma unroll
  for (int f = 0; f < 4; ++f) {
    int ra = wm * 64 + f * 16 + ln;
    aoff[f][0] = (ra * 8 + ((q)     ^ (ra & 7))) * 8;
    aoff[f][1] = (ra * 8 + ((q + 4) ^ (ra & 7))) * 8;
    int rb = wn * 64 + f * 16 + ln;
    boff[f][0] = (rb * 8 + ((q)     ^ (rb & 7))) * 8;
    boff[f][1] = (rb * 8 + ((q + 4) ^ (rb & 7))) * 8;
  }
  int sgo[4];
#pragma unroll
  for (int i = 0; i < 4; ++i) {
    int s = i * 256 + tid;
    int row = s >> 3;
    int c8 = (s & 7) ^ (row & 7);
    sgo[i] = row * KDIM + c8 * 8;
  }
  // prologue: stage k0=0 into buffer 0
#pragma unroll
  for (int i = 0; i < 4; ++i) {
    gl2lds16(Ab + sgo[i], ldsA + (i * 256 + wave * 64) * 8);
    gl2lds16(Bb + sgo[i], ldsB + (i * 256 + wave * 64) * 8);
  }
  __syncthreads();

  for (int k0 = 0; k0 < KDIM; k0 += 64) {
    const int cur = (k0 >> 6) & 1;
    unsigned short* A = ldsA + cur * (128 * 64);
    unsigned short* B = ldsB + cur * (128 * 64);
    if (k0 + 64 < KDIM) {
      unsigned short* An = ldsA + (cur ^ 1) * (128 * 64);
      unsigned short* Bn = ldsB + (cur ^ 1) * (128 * 64);
#pragma unroll
      for (int i = 0; i < 4; ++i) {
        gl2lds16(Ab + sgo[i] + k0 + 64, An + (i * 256 + wave * 64) * 8);
        gl2lds16(Bb + sgo[i] + k0 + 64, Bn + (i * 256 + wave * 64) * 8);
      }
    }
#pragma unroll
    for (int kk = 0; kk < 2; ++kk) {
      bf16x8 af[4], bfr[4];
#pragma unroll
      for (int f = 0; f < 4; ++f) af[f]  = *(const bf16x8*)(A + aoff[f][kk]);
#pragma unroll
      for (int f = 0; f < 4; ++f) bfr[f] = *(const bf16x8*)(B + boff[f][kk]);
#pragma unroll
      for (int mf = 0; mf < 4; ++mf)
#pragma unroll
        for (int nf = 0; nf < 4; ++nf)
          acc[mf][nf] = mfma16(af[mf], bfr[nf], acc[mf][nf]);
    }
    __syncthreads();
  }
}

// -------------------------------- 256x128 NT GEMM core (convout, K=256)
DEVI void gemm256(const unsigned short* __restrict__ Ab,
                  const unsigned short* __restrict__ Bb,
                  unsigned short* ldsA,               // [256*64]
                  unsigned short* ldsB,               // [128*64]
                  f32x4 acc[8][4], int tid)
{
  const int lane = tid & 63, wave = tid >> 6;
  const int q = lane >> 4, ln = lane & 15;
  const int wm = wave & 1, wn = wave >> 1;

  int aoff[8][2], boff[4][2];
#pragma unroll
  for (int f = 0; f < 8; ++f) {
    int ra = wm * 128 + f * 16 + ln;
    aoff[f][0] = (ra * 8 + ((q)     ^ (ra & 7))) * 8;
    aoff[f][1] = (ra * 8 + ((q + 4) ^ (ra & 7))) * 8;
  }
#pragma unroll
  for (int f = 0; f < 4; ++f) {
    int rb = wn * 64 + f * 16 + ln;
    boff[f][0] = (rb * 8 + ((q)     ^ (rb & 7))) * 8;
    boff[f][1] = (rb * 8 + ((q + 4) ^ (rb & 7))) * 8;
  }
  int sgoA[8], sgoB[4];
#pragma unroll
  for (int i = 0; i < 8; ++i) {
    int s = i * 256 + tid;
    int row = s >> 3;
    int c8 = (s & 7) ^ (row & 7);
    sgoA[i] = row * CI + c8 * 8;
  }
#pragma unroll
  for (int i = 0; i < 4; ++i) {
    int s = i * 256 + tid;
    int row = s >> 3;
    int c8 = (s & 7) ^ (row & 7);
    sgoB[i] = row * CI + c8 * 8;
  }
  for (int k0 = 0; k0 < CI; k0 += 64) {
#pragma unroll
    for (int i = 0; i < 8; ++i)
      gl2lds16(Ab + sgoA[i] + k0, ldsA + (i * 256 + wave * 64) * 8);
#pragma unroll
    for (int i = 0; i < 4; ++i)
      gl2lds16(Bb + sgoB[i] + k0, ldsB + (i * 256 + wave * 64) * 8);
    __syncthreads();
#pragma unroll
    for (int kk = 0; kk < 2; ++kk) {
      bf16x8 af[8], bfr[4];
#pragma unroll
      for (int f = 0; f < 8; ++f) af[f]  = *(const bf16x8*)(ldsA + aoff[f][kk]);
#pragma unroll
      for (int f = 0; f < 4; ++f) bfr[f] = *(const bf16x8*)(ldsB + boff[f][kk]);
#pragma unroll
      for (int mf = 0; mf < 8; ++mf)
#pragma unroll
        for (int nf = 0; nf < 4; ++nf)
          acc[mf][nf] = mfma16(af[mf], bfr[nf], acc[mf][nf]);
    }
    __syncthreads();
  }
}

// ------------------------------------------------- qk/value conv (fused)
// R6 config (reverted): 128x128 dbuf tile, 256 threads, grid (32,4,4).
// value blocks use swapped operands -> packed 8B vv writes.
__global__ __launch_bounds__(256) void k_convqkv(
    const unsigned short* __restrict__ wkv,   // [512][1024]
    const unsigned short* __restrict__ xT,    // [B][4096][1024]
    const float* __restrict__ sq, const float* __restrict__ bq,
    const float* __restrict__ bval,
    unsigned short* __restrict__ qkT,         // [B][4096][256]
    unsigned short* __restrict__ vv)          // [B][256][4096]
{
  __shared__ __align__(16) unsigned short ldsA[2 * 128 * 64];
  __shared__ __align__(16) unsigned short ldsB[2 * 128 * 64];
  int b = blockIdx.z, m0 = blockIdx.y * 128, n0 = blockIdx.x * 128;
  int tid = threadIdx.x;
  f32x4 z = {0.f, 0.f, 0.f, 0.f};
  f32x4 acc[4][4];
#pragma unroll
  for (int i = 0; i < 4; ++i)
#pragma unroll
    for (int j = 0; j < 4; ++j) acc[i][j] = z;

  const unsigned short* wp = wkv + (size_t)m0 * CIN;
  const unsigned short* xp = xT + ((size_t)b * NSP + n0) * CIN;
  bool qk = (m0 < 256);
  gemm_core_db<CIN>(qk ? wp : xp, qk ? xp : wp, ldsA, ldsB, acc, tid);

  int lane = tid & 63, wave = tid >> 6, q = lane >> 4, ln = lane & 15;
  int wm = wave & 1, wn = wave >> 1;
  if (qk) {
    // D rows = channels (wkv), cols = spatial
#pragma unroll
    for (int mf = 0; mf < 4; ++mf) {
      int cb = m0 + wm * 64 + mf * 16 + q * 4;
      float s0_ = sq[cb + 0], s1_ = sq[cb + 1], s2_ = sq[cb + 2], s3_ = sq[cb + 3];
      float b0_ = bq[cb + 0], b1_ = bq[cb + 1], b2_ = bq[cb + 2], b3_ = bq[cb + 3];
#pragma unroll
      for (int nf = 0; nf < 4; ++nf) {
        int n = n0 + wn * 64 + nf * 16 + ln;
        uint2v pk2;
        pk2.x = cvtpk(acc[mf][nf][0] * s0_ + b0_, acc[mf][nf][1] * s1_ + b1_);
        pk2.y = cvtpk(acc[mf][nf][2] * s2_ + b2_, acc[mf][nf][3] * s3_ + b3_);
        *(uint2v*)(qkT + ((size_t)b * NSP + n) * CI + cb) = pk2;
      }
    }
  } else {
    // D rows = spatial (xT), cols = value channels
    int c0 = m0 - 256;
#pragma unroll
    for (int nf = 0; nf < 4; ++nf) {
      int c = c0 + wn * 64 + nf * 16 + ln;
      float bv = bval[c];
      unsigned short* vr = vv + ((size_t)b * CI + c) * NSP + n0 + wm * 64 + q * 4;
#pragma unroll
      for (int mf = 0; mf < 4; ++mf) {
        uint2v wv2;
        wv2.x = cvtpk(acc[mf][nf][0] + bv, acc[mf][nf][1] + bv);
        wv2.y = cvtpk(acc[mf][nf][2] + bv, acc[mf][nf][3] + bv);
        *(uint2v*)(vr + mf * 16) = wv2;
      }
    }
  }
}

// ------------------------------------------------- fused attention, partial
// R12: 8-wave blocks (512 threads), 256 blocks = 1 block/CU. K/V staging
// shared by 8 waves instead of 4 -> per-CU staging DMA + L2 read traffic
// halves vs the 2x4-wave layout; occupancy unchanged (2 waves/SIMD).
// LDS: Kt 32 KB + Vt 32 KB + Pl 20 KB = 84 KB.
__global__ __launch_bounds__(512, 2) void k_attn_part(
    const unsigned short* __restrict__ qkT,   // [B][4096][256]
    const unsigned short* __restrict__ vv,    // [B][256][4096]
    unsigned* __restrict__ Opart,             // [256][128 rowpair][256] u32
    float* __restrict__ Lpart)                // [256][256]
{
  __shared__ __align__(16) unsigned short Kt[2][32 * 256]; // [32 j][32 cc] swz
  __shared__ __align__(16) unsigned short Vt[2][256 * 32]; // [256 c][4 cc] swz
  __shared__ __align__(16) unsigned short Pl[8 * 32 * 40]; // per-wave [32 m][40]

  int bid = blockIdx.x;                       // 256 blocks
  int slice = bid & 15, qt = bid >> 4;        // qt 0..15 (256 rows each)
  int b = slice >> 2, js = slice & 3;
  int n0 = qt * 256;
  int tid = threadIdx.x, lane = tid & 63, wave = tid >> 6;   // wave 0..7
  int q = lane >> 4, ln = lane & 15;
  const unsigned short* qkb = qkT + (size_t)b * NSP * CI;
  const unsigned short* vb  = vv  + (size_t)b * CI * NSP;

  // Q fragments: wave's 32 q-rows (rows wave*32 + {ln, 16+ln}), 256 channels
  bf16x8 Qf0[8], Qf1[8];
  {
    const unsigned short* qr0 = qkb + (size_t)(n0 + wave * 32 + ln) * CI + q * 8;
    const unsigned short* qr1 = qr0 + 16 * CI;
#pragma unroll
    for (int t = 0; t < 8; ++t) Qf0[t] = *(const bf16x8*)(qr0 + t * 32);
#pragma unroll
    for (int t = 0; t < 8; ++t) Qf1[t] = *(const bf16x8*)(qr1 + t * 32);
  }

  int kbA = (ln * 32 + ((q ^ (ln & 7)) & 7)) * 8;            // t even
  int kbB = (ln * 32 + (((4 + q) ^ (ln & 7)) & 7)) * 8;      // t odd
  int vbase = (ln * 4 + ((q ^ ((ln >> 1) & 3)) & 3)) * 8;

  unsigned short* Plw = Pl + wave * (32 * 40);
  int pw0 = ln * 40 + q * 4;
  int pw1 = ln * 40 + 16 + q * 4;
  int pw2 = (ln + 16) * 40 + q * 4;
  int pw3 = (ln + 16) * 40 + 16 + q * 4;
  int pr0 = ln * 40 + q * 8;
  int pr1 = (ln + 16) * 40 + q * 8;

  // staging offsets: 512 threads cover each 16 KB tile in 2 gl2lds16 rounds
  int gko[2], gvo[2];
#pragma unroll
  for (int i = 0; i < 2; ++i) {
    int s = i * 512 + tid;
    int j = s >> 5, f = s & 31;
    gko[i] = j * CI + ((f & 24) | ((f ^ j) & 7)) * 8;
    int c = s >> 2;
    gvo[i] = c * NSP + ((s ^ (c >> 1)) & 3) * 8;
  }

  f32x4 O0[16], O1[16];
  f32x4 z = {0.f, 0.f, 0.f, 0.f};
#pragma unroll
  for (int cf = 0; cf < 16; ++cf) { O0[cf] = z; O1[cf] = z; }
  float l0c = 0.f, l1c = 0.f;

  int jbase = js * 1024;

#pragma unroll
  for (int i = 0; i < 2; ++i) {
    gl2lds16(qkb + (size_t)jbase * CI + gko[i], &Kt[0][(i * 512 + wave * 64) * 8]);
    gl2lds16(vb + jbase + gvo[i], &Vt[0][(i * 512 + wave * 64) * 8]);
  }
  __syncthreads();

  for (int it = 0; it < 32; ++it) {
    int cur = it & 1;

    if (it < 31) {
      int j1 = jbase + (it + 1) * 32;
#pragma unroll
      for (int i = 0; i < 2; ++i) {
        gl2lds16(qkb + (size_t)j1 * CI + gko[i],
                 &Kt[cur ^ 1][(i * 512 + wave * 64) * 8]);
        gl2lds16(vb + j1 + gvo[i],
                 &Vt[cur ^ 1][(i * 512 + wave * 64) * 8]);
      }
    }

    const unsigned short* Kc = Kt[cur];
    const unsigned short* Vc = Vt[cur];

    f32x4 s0 = z, s1 = z, s2 = z, s3 = z;
    __builtin_amdgcn_s_setprio(1);
#pragma unroll
    for (int t = 0; t < 8; ++t) {
      int ko = ((t & 1) ? kbB : kbA) + (t >> 1) * 64;
      bf16x8 kf0 = *(const bf16x8*)(Kc + ko);
      bf16x8 kf1 = *(const bf16x8*)(Kc + ko + 4096);
      s0 = mfma16(kf0, Qf0[t], s0);
      s1 = mfma16(kf1, Qf0[t], s1);
      s2 = mfma16(kf0, Qf1[t], s2);
      s3 = mfma16(kf1, Qf1[t], s3);
    }
    __builtin_amdgcn_s_setprio(0);

    float p00 = __expf(s0[0]), p01 = __expf(s0[1]);
    float p02 = __expf(s0[2]), p03 = __expf(s0[3]);
    float p04 = __expf(s1[0]), p05 = __expf(s1[1]);
    float p06 = __expf(s1[2]), p07 = __expf(s1[3]);
    float p10 = __expf(s2[0]), p11 = __expf(s2[1]);
    float p12 = __expf(s2[2]), p13 = __expf(s2[3]);
    float p14 = __expf(s3[0]), p15 = __expf(s3[1]);
    float p16 = __expf(s3[2]), p17 = __expf(s3[3]);

    uint2v w;
    w.x = cvtpk(p00, p01); w.y = cvtpk(p02, p03);
    *(uint2v*)(Plw + pw0) = w;
    w.x = cvtpk(p04, p05); w.y = cvtpk(p06, p07);
    *(uint2v*)(Plw + pw1) = w;
    w.x = cvtpk(p10, p11); w.y = cvtpk(p12, p13);
    *(uint2v*)(Plw + pw2) = w;
    w.x = cvtpk(p14, p15); w.y = cvtpk(p16, p17);
    *(uint2v*)(Plw + pw3) = w;

    l0c += ((p00 + p01) + (p02 + p03)) + ((p04 + p05) + (p06 + p07));
    l1c += ((p10 + p11) + (p12 + p13)) + ((p14 + p15) + (p16 + p17));

    bf16x8 pf0 = *(const bf16x8*)(Plw + pr0);
    bf16x8 pf1 = *(const bf16x8*)(Plw + pr1);
    __builtin_amdgcn_s_setprio(1);
#pragma unroll
    for (int cf = 0; cf < 16; ++cf) {
      bf16x8 vf = *(const bf16x8*)(Vc + vbase + cf * 512);
      O0[cf] = mfma16(pf0, vf, O0[cf]);
      O1[cf] = mfma16(pf1, vf, O1[cf]);
    }
    __builtin_amdgcn_s_setprio(0);

    __syncthreads();
  }

  l0c += __shfl_xor(l0c, 16); l0c += __shfl_xor(l0c, 32);
  l1c += __shfl_xor(l1c, 16); l1c += __shfl_xor(l1c, 32);

  unsigned* Ob = Opart + (size_t)bid * (128 * 256);
  if (lane < 16) {
    Lpart[bid * 256 + wave * 32 + lane] = l0c;
    Lpart[bid * 256 + wave * 32 + 16 + lane] = l1c;
  }
  // packed write: rowpair rp -> rows (rp>>4)*32 + (rp&15) and +16
#pragma unroll
  for (int r = 0; r < 4; ++r) {
    int rp = wave * 16 + q * 4 + r;           // 0..127
#pragma unroll
    for (int cf = 0; cf < 16; ++cf)
      Ob[rp * 256 + cf * 16 + ln] = cvtpk(O0[cf][r], O1[cf][r]);
  }
}

// ------------------------------------------------- split-k softmax merge
// Opart: [256 bid][128 rp][256 c]; bid = qt8*16 + b*4 + js; block rows 256.
// Merge block handles (b, qg): global rows qg*64..+64 = block qt8 = qg>>2,
// quarter = qg&3, rowpairs quarter*32 + [0,32).
__global__ __launch_bounds__(256) void k_merge(
    const unsigned* __restrict__ Opart,       // [256][128][256] u32
    const float* __restrict__ Lpart,          // [256][256]
    unsigned short* __restrict__ ctx)         // [B][4096][256]
{
  __shared__ float Winv[64];
  int mb = blockIdx.x;                        // 256: one per (b, 64-row group)
  int b = mb >> 6, qg = mb & 63;
  int qt8 = qg >> 2, quarter = qg & 3;
  int tid = threadIdx.x;
  int pb0 = qt8 * 16 + b * 4;                 // partial block base (js=0..3)

  if (tid < 64) {
    int row = quarter * 64 + tid;             // row within the 256-row block
    float L = Lpart[(pb0 + 0) * 256 + row]
            + Lpart[(pb0 + 1) * 256 + row]
            + Lpart[(pb0 + 2) * 256 + row]
            + Lpart[(pb0 + 3) * 256 + row];
    Winv[tid] = 1.0f / L;
  }
  __syncthreads();

  const unsigned* P0 = Opart + ((size_t)(pb0 + 0) * 128 + quarter * 32) * 256;
  const unsigned* P1 = Opart + ((size_t)(pb0 + 1) * 128 + quarter * 32) * 256;
  const unsigned* P2 = Opart + ((size_t)(pb0 + 2) * 128 + quarter * 32) * 256;
  const unsigned* P3 = Opart + ((size_t)(pb0 + 3) * 128 + quarter * 32) * 256;
  unsigned short* cb = ctx + ((size_t)b * NSP + qg * 64) * CI;
#pragma unroll 4
  for (int rp = 0; rp < 32; ++rp) {
    unsigned u0 = P0[rp * 256 + tid], u1 = P1[rp * 256 + tid];
    unsigned u2 = P2[rp * 256 + tid], u3 = P3[rp * 256 + tid];
    float lo = __uint_as_float(u0 << 16) + __uint_as_float(u1 << 16)
             + __uint_as_float(u2 << 16) + __uint_as_float(u3 << 16);
    float hi = __uint_as_float(u0 & 0xFFFF0000u) + __uint_as_float(u1 & 0xFFFF0000u)
             + __uint_as_float(u2 & 0xFFFF0000u) + __uint_as_float(u3 & 0xFFFF0000u);
    int ra = (rp & 15) + ((rp >> 4) << 5);    // local row in the 64-row group
    int rb = ra + 16;
    cb[(size_t)ra * CI + tid] = f2bf(lo * Winv[ra]);
    cb[(size_t)rb * CI + tid] = f2bf(hi * Winv[rb]);
  }
}

// ------------------------------------------------------ output conv
// R6 config (reverted): 256x128 tile, 256 threads, grid (32,4,4).
__global__ __launch_bounds__(256) void k_convout(
    const unsigned short* __restrict__ wo,    // [1024][256]
    const unsigned short* __restrict__ ctx,   // [B][4096][256]
    const float* __restrict__ bout,
    float* __restrict__ out)                  // [B][1024][4096]
{
  __shared__ __align__(16) unsigned short ldsA[256 * 64];
  __shared__ __align__(16) unsigned short ldsB[128 * 64];
  int b = blockIdx.z, m0 = blockIdx.y * 256, n0 = blockIdx.x * 128;
  int tid = threadIdx.x;
  f32x4 z = {0.f, 0.f, 0.f, 0.f};
  f32x4 acc[8][4];
#pragma unroll
  for (int i = 0; i < 8; ++i)
#pragma unroll
    for (int j = 0; j < 4; ++j) acc[i][j] = z;

  gemm256(wo + (size_t)m0 * CI, ctx + ((size_t)b * NSP + n0) * CI,
          ldsA, ldsB, acc, tid);

  int lane = tid & 63, wave = tid >> 6, q = lane >> 4, ln = lane & 15;
  int wm = wave & 1, wn = wave >> 1;
#pragma unroll
  for (int mf = 0; mf < 8; ++mf) {
    int cb = m0 + wm * 128 + mf * 16 + q * 4;
    float bo0 = bout[cb + 0], bo1 = bout[cb + 1], bo2 = bout[cb + 2], bo3 = bout[cb + 3];
#pragma unroll
    for (int nf = 0; nf < 4; ++nf) {
      int n = n0 + wn * 64 + nf * 16 + ln;
      float* p = out + ((size_t)b * CO + cb) * NSP + n;
      p[0 * (size_t)NSP] = acc[mf][nf][0] + bo0;
      p[1 * (size_t)NSP] = acc[mf][nf][1] + bo1;
      p[2 * (size_t)NSP] = acc[mf][nf][2] + bo2;
      p[3 * (size_t)NSP] = acc[mf][nf][3] + bo3;
    }
  }
}

// ---------------------------------------------------------------- launch
extern "C" void kernel_launch(void* const* d_in, const int* in_sizes, int n_in,
                              void* d_out, int out_size, void* d_ws, size_t ws_size,
                              hipStream_t stream) {
  const float* x     = (const float*)d_in[0];
  const float* w_key = (const float*)d_in[1];
  const float* b_key = (const float*)d_in[2];
  const float* gamma = (const float*)d_in[3];
  const float* beta  = (const float*)d_in[4];
  const float* mean  = (const float*)d_in[5];
  const float* var   = (const float*)d_in[6];
  const float* w_val = (const float*)d_in[7];
  const float* b_val = (const float*)d_in[8];
  const float* w_out = (const float*)d_in[9];
  const float* b_out = (const float*)d_in[10];
  float* out = (float*)d_out;

  char* ws = (char*)d_ws;
  unsigned short* xT  = (unsigned short*)(ws);               // 32 MiB
  unsigned short* wkv = (unsigned short*)(ws + 33554432);    // 1 MiB
  unsigned short* wob = (unsigned short*)(ws + 34603008);    // 512 KiB
  unsigned short* qkT = (unsigned short*)(ws + 35127296);    // 8 MiB
  unsigned short* vv  = (unsigned short*)(ws + 43515904);    // 8 MiB
  unsigned short* ctx = (unsigned short*)(ws + 51904512);    // 8 MiB
  float* sq = (float*)(ws + 60293120);                       // 1 KiB
  float* bq = (float*)(ws + 60294144);                       // 1 KiB
  unsigned* Opart = (unsigned*)(ws + 60295168);              // 32 MiB (packed)
  float* Lpart = (float*)(ws + 127404032);                   // 256 KiB

  k_xpose_prep<<<6144, 256, 0, stream>>>(x, xT, w_key, w_val, w_out, gamma,
                                         beta, mean, var, b_key, wkv, wob,
                                         sq, bq);
  k_convqkv<<<dim3(32, 4, 4), 256, 0, stream>>>(wkv, xT, sq, bq, b_val, qkT, vv);
  k_attn_part<<<256, 512, 0, stream>>>(qkT, vv, Opart, Lpart);
  k_merge<<<256, 256, 0, stream>>>(Opart, Lpart, ctx);
  k_convout<<<dim3(32, 4, 4), 256, 0, stream>>>(wob, ctx, b_out, out);
}